// Round 3
// baseline (433.590 us; speedup 1.0000x reference)
//
#include <hip/hip_runtime.h>

#define TPB 256

// ---------------------------------------------------------------------------
// Dispatch A: 4-way GEMV partial sums, float4 loads along rows.
//   pu[chunk][j] = sum_{k in chunk} pos[k]*U[k][j] + neg[k]*O[k][j]
//   po[chunk][j] = sum_{k in chunk} pos[k]*O[k][j] + neg[k]*U[k][j]
// Grid: nchunks * (vec_tiles + 1). Vec tiles cover 1024 columns each with one
// float4 per thread (rows are contiguous; loads are 4B-aligned for 3 of 4
// rows — gfx950 global memory handles unaligned dwordx4). Tail tile covers
// the remaining (ncols % 1024) columns scalarly. Partials use padded stride
// ps (multiple of 8) so partial stores stay 16B-aligned.
// ---------------------------------------------------------------------------
__global__ __launch_bounds__(TPB) void gemv_vec(
    const float* __restrict__ U, const float* __restrict__ O,
    const float* __restrict__ pos, const float* __restrict__ neg,
    float* __restrict__ pu, float* __restrict__ po,
    int K, int ncols, int ps, int vec_tiles, int rpc) {
  const int tiles_total = vec_tiles + 1;
  const int chunk = blockIdx.x / tiles_total;
  const int tile  = blockIdx.x % tiles_total;
  const int k0 = chunk * rpc;
  int k1 = k0 + rpc; if (k1 > K) k1 = K;

  if (tile < vec_tiles) {
    const int j = (tile * TPB + threadIdx.x) * 4;   // j+3 <= vec_tiles*1024-1 < ncols
    float4 au = make_float4(0.f, 0.f, 0.f, 0.f);
    float4 ao = make_float4(0.f, 0.f, 0.f, 0.f);
    const float* Ub = U + j;
    const float* Ob = O + j;
    int k = k0;
    for (; k + 4 <= k1; k += 4) {
      float p[4], n[4];
      float4 a[4], b[4];
#pragma unroll
      for (int u = 0; u < 4; ++u) {
        p[u] = pos[k + u];
        n[u] = neg[k + u];
        a[u] = *reinterpret_cast<const float4*>(Ub + (size_t)(k + u) * ncols);
        b[u] = *reinterpret_cast<const float4*>(Ob + (size_t)(k + u) * ncols);
      }
#pragma unroll
      for (int u = 0; u < 4; ++u) {
        au.x = fmaf(p[u], a[u].x, au.x); au.y = fmaf(p[u], a[u].y, au.y);
        au.z = fmaf(p[u], a[u].z, au.z); au.w = fmaf(p[u], a[u].w, au.w);
        au.x = fmaf(n[u], b[u].x, au.x); au.y = fmaf(n[u], b[u].y, au.y);
        au.z = fmaf(n[u], b[u].z, au.z); au.w = fmaf(n[u], b[u].w, au.w);
        ao.x = fmaf(p[u], b[u].x, ao.x); ao.y = fmaf(p[u], b[u].y, ao.y);
        ao.z = fmaf(p[u], b[u].z, ao.z); ao.w = fmaf(p[u], b[u].w, ao.w);
        ao.x = fmaf(n[u], a[u].x, ao.x); ao.y = fmaf(n[u], a[u].y, ao.y);
        ao.z = fmaf(n[u], a[u].z, ao.z); ao.w = fmaf(n[u], a[u].w, ao.w);
      }
    }
    for (; k < k1; ++k) {
      float p = pos[k], n = neg[k];
      float4 a = *reinterpret_cast<const float4*>(Ub + (size_t)k * ncols);
      float4 b = *reinterpret_cast<const float4*>(Ob + (size_t)k * ncols);
      au.x = fmaf(p, a.x, au.x); au.y = fmaf(p, a.y, au.y);
      au.z = fmaf(p, a.z, au.z); au.w = fmaf(p, a.w, au.w);
      au.x = fmaf(n, b.x, au.x); au.y = fmaf(n, b.y, au.y);
      au.z = fmaf(n, b.z, au.z); au.w = fmaf(n, b.w, au.w);
      ao.x = fmaf(p, b.x, ao.x); ao.y = fmaf(p, b.y, ao.y);
      ao.z = fmaf(p, b.z, ao.z); ao.w = fmaf(p, b.w, ao.w);
      ao.x = fmaf(n, a.x, ao.x); ao.y = fmaf(n, a.y, ao.y);
      ao.z = fmaf(n, a.z, ao.z); ao.w = fmaf(n, a.w, ao.w);
    }
    *reinterpret_cast<float4*>(pu + (size_t)chunk * ps + j) = au;
    *reinterpret_cast<float4*>(po + (size_t)chunk * ps + j) = ao;
  } else {
    // Tail columns [vec_tiles*1024, ncols)
    for (int j = vec_tiles * TPB * 4 + threadIdx.x; j < ncols; j += TPB) {
      float au = 0.f, ao = 0.f;
#pragma unroll 4
      for (int k = k0; k < k1; ++k) {
        float p = pos[k], n = neg[k];
        float a = U[(size_t)k * ncols + j];
        float b = O[(size_t)k * ncols + j];
        au = fmaf(p, a, au); au = fmaf(n, b, au);
        ao = fmaf(p, b, ao); ao = fmaf(n, a, ao);
      }
      pu[(size_t)chunk * ps + j] = au;
      po[(size_t)chunk * ps + j] = ao;
    }
  }
}

// ---------------------------------------------------------------------------
// Dispatch B (pow2 path): fill both IBF tensors AND finish row 0 inline.
// One float4 = rows r0, r0+1 (cols 0..1 each) of one block. Threads whose
// float4 starts a block (within==0, i.e. row 0) reduce the GEMV partials for
// their block's coefficient (visible because dispatch A completed in stream
// order), add bias, and scale elements .x/.y. Also writes the ones degree
// vectors. Exactly one launch; no separate finisher.
// ---------------------------------------------------------------------------
__global__ __launch_bounds__(TPB) void fill_finish(
    const float* __restrict__ intervals,
    const float* __restrict__ pu, const float* __restrict__ po,
    const float* __restrict__ bias_p,
    float* __restrict__ outU, float* __restrict__ outO,
    float* __restrict__ degs,
    int n_vars, int shift, int mask, int n4total, int nchunks, int ps) {
  int i4 = blockIdx.x * TPB + threadIdx.x;
  if (i4 < 2 * n_vars) degs[i4] = 1.0f;
  if (i4 >= n4total) return;

  int i = i4 << 2;
  int blk = i >> shift;          // block index in [0, n_vars]
  int within = i & mask;         // multiple of 4
  int r0 = within >> 1;          // even row; float4 = rows r0, r0+1

  float4 v = make_float4(1.f, 1.f, 1.f, 1.f);
  if (r0 == blk) {               // diag at even row (never hits blk==n_vars)
    v.x = intervals[2 * blk];
    v.y = intervals[2 * blk + 1];
  } else if (r0 + 1 == blk) {    // diag at odd row
    v.z = intervals[2 * blk];
    v.w = intervals[2 * blk + 1];
  }

  float4 vu = v, vo = v;
  if (within == 0) {             // this float4 holds row 0 (and row 1)
    float bb = bias_p[0];
    float su = bb, so = bb;
#pragma unroll 8
    for (int c = 0; c < nchunks; ++c) {
      su += pu[(size_t)c * ps + blk];
      so += po[(size_t)c * ps + blk];
    }
    vu.x = v.x * su; vu.y = v.y * su;
    vo.x = v.x * so; vo.y = v.y * so;
  }

  reinterpret_cast<float4*>(outU)[i4] = vu;
  reinterpret_cast<float4*>(outO)[i4] = vo;
}

// ---------------------------------------------------------------------------
// Generic fallbacks (non-pow2 n_vars): base fill + separate finisher.
// ---------------------------------------------------------------------------
__global__ __launch_bounds__(TPB) void fill_scalar(
    const float* __restrict__ intervals,
    float* __restrict__ outU, float* __restrict__ outO,
    int n_vars, long long S) {
  long long tid = (long long)blockIdx.x * blockDim.x + threadIdx.x;
  long long nthreads = (long long)gridDim.x * blockDim.x;
  int two_n = 2 * n_vars;
  for (long long i = tid; i < S; i += nthreads) {
    int blk = (int)(i / two_n);
    int within = (int)(i - (long long)blk * two_n);
    int r = within >> 1;
    int c = within & 1;
    float v = 1.f;
    if (r == blk) v = intervals[2 * r + c];
    outU[i] = v;
    outO[i] = v;
  }
}

__global__ __launch_bounds__(TPB) void finish(
    const float* __restrict__ pu, const float* __restrict__ po,
    const float* __restrict__ intervals, const float* __restrict__ bias_p,
    float* __restrict__ outU, float* __restrict__ outO,
    float* __restrict__ degs,
    int ncols, int n_vars, int nchunks, int ps) {
  int t = blockIdx.x * TPB + threadIdx.x;
  int two_n = 2 * n_vars;
  if (t < two_n) degs[t] = 1.0f;
  if (t < ncols) {
    float s = bias_p[0];
    for (int c = 0; c < nchunks; ++c) s += pu[(size_t)c * ps + t];
    float vx = s, vy = s;
    if (t == 0) { vx = intervals[0] * s; vy = intervals[1] * s; }
    size_t off = (size_t)t * two_n;
    outU[off] = vx; outU[off + 1] = vy;
  } else if (t < 2 * ncols) {
    int j = t - ncols;
    float s = bias_p[0];
    for (int c = 0; c < nchunks; ++c) s += po[(size_t)c * ps + j];
    float vx = s, vy = s;
    if (j == 0) { vx = intervals[0] * s; vy = intervals[1] * s; }
    size_t off = (size_t)j * two_n;
    outO[off] = vx; outO[off + 1] = vy;
  }
}

extern "C" void kernel_launch(void* const* d_in, const int* in_sizes, int n_in,
                              void* d_out, int out_size, void* d_ws, size_t ws_size,
                              hipStream_t stream) {
  const float* U         = (const float*)d_in[0];  // (K, n_vars+1)
  const float* O         = (const float*)d_in[1];  // (K, n_vars+1)
  const float* intervals = (const float*)d_in[4];  // (n_vars, 2)
  const float* pos       = (const float*)d_in[5];  // (K,)
  const float* neg       = (const float*)d_in[6];  // (K,)
  const float* bias      = (const float*)d_in[7];  // (1,)

  const int n_vars = in_sizes[4] / 2;
  const int K      = in_sizes[5];
  const int ncols  = n_vars + 1;
  const int ps     = (ncols + 7) & ~7;   // padded partial stride (16B-aligned rows)

  int nchunks = 128;
  while (nchunks > 1 && (size_t)2 * nchunks * ps * sizeof(float) > ws_size)
    nchunks >>= 1;
  const int rpc = (K + nchunks - 1) / nchunks;
  float* pu = (float*)d_ws;
  float* po = pu + (size_t)nchunks * ps;

  const int vec_tiles = ncols / (TPB * 4);  // 1024-column vec tiles

  // Dispatch A: GEMV partials (read-bound, ~134 MB fetch).
  gemv_vec<<<nchunks * (vec_tiles + 1), TPB, 0, stream>>>(
      U, O, pos, neg, pu, po, K, ncols, ps, vec_tiles, rpc);

  const long long S = (long long)ncols * n_vars * 2;  // elements per tensor
  float* outU = (float*)d_out;
  float* outO = outU + S;
  float* degs = outU + 2 * S;

  const int two_n = 2 * n_vars;
  const bool pow2 = two_n > 0 && (two_n & (two_n - 1)) == 0;

  if (pow2 && S / 4 < (1LL << 31)) {
    // Dispatch B: fill + inline finish (write-bound, ~269 MB write).
    int shift = __builtin_ctz((unsigned)two_n);
    int n4 = (int)(S / 4);
    long long nthreads = n4 > two_n ? n4 : two_n;
    int blocks = (int)((nthreads + TPB - 1) / TPB);
    fill_finish<<<blocks, TPB, 0, stream>>>(
        intervals, pu, po, bias, outU, outO, degs,
        n_vars, shift, two_n - 1, n4, nchunks, ps);
  } else {
    fill_scalar<<<4096, TPB, 0, stream>>>(intervals, outU, outO, n_vars, S);
    int nB = (2 * ncols > two_n ? 2 * ncols : two_n);
    finish<<<(nB + TPB - 1) / TPB, TPB, 0, stream>>>(
        pu, po, intervals, bias, outU, outO, degs, ncols, n_vars, nchunks, ps);
  }
}

// Round 4
// 396.615 us; speedup vs baseline: 1.0932x; 1.0932x over previous
//
#include <hip/hip_runtime.h>

#define TPB 256

// ---------------------------------------------------------------------------
// Dispatch A: 4-way GEMV partial sums. Scalar dword loads — consecutive lanes
// read consecutive columns (fully coalesced, 256 B/wave/instr). ncols is odd
// (4097) so vector loads would be misaligned (R3 regression: -48 us); scalar
// is the right form here.
//   pu[chunk][j] = sum_{k in chunk} pos[k]*U[k][j] + neg[k]*O[k][j]
//   po[chunk][j] = sum_{k in chunk} pos[k]*O[k][j] + neg[k]*U[k][j]
// pos/neg are wave-uniform loads (k independent of threadIdx) -> s_load.
// ---------------------------------------------------------------------------
__global__ __launch_bounds__(TPB) void gemv4(
    const float* __restrict__ U, const float* __restrict__ O,
    const float* __restrict__ pos, const float* __restrict__ neg,
    float* __restrict__ pu, float* __restrict__ po,
    int K, int ncols, int ps, int col_tiles, int rpc) {
  const int chunk = blockIdx.x / col_tiles;
  const int tile  = blockIdx.x % col_tiles;
  const int j = tile * TPB + threadIdx.x;
  if (j >= ncols) return;
  const int k0 = chunk * rpc;
  int k1 = k0 + rpc; if (k1 > K) k1 = K;

  const size_t st = (size_t)ncols;
  const float* Uq = U + (size_t)k0 * st + j;
  const float* Oq = O + (size_t)k0 * st + j;
  float au = 0.f, ao = 0.f;
  int k = k0;
  for (; k + 4 <= k1; k += 4) {
    float p0 = pos[k],   p1 = pos[k+1], p2 = pos[k+2], p3 = pos[k+3];
    float n0 = neg[k],   n1 = neg[k+1], n2 = neg[k+2], n3 = neg[k+3];
    float a0 = Uq[0], a1 = Uq[st], a2 = Uq[2*st], a3 = Uq[3*st];
    float b0 = Oq[0], b1 = Oq[st], b2 = Oq[2*st], b3 = Oq[3*st];
    Uq += 4*st; Oq += 4*st;
    au = fmaf(p0, a0, au); au = fmaf(n0, b0, au);
    ao = fmaf(p0, b0, ao); ao = fmaf(n0, a0, ao);
    au = fmaf(p1, a1, au); au = fmaf(n1, b1, au);
    ao = fmaf(p1, b1, ao); ao = fmaf(n1, a1, ao);
    au = fmaf(p2, a2, au); au = fmaf(n2, b2, au);
    ao = fmaf(p2, b2, ao); ao = fmaf(n2, a2, ao);
    au = fmaf(p3, a3, au); au = fmaf(n3, b3, au);
    ao = fmaf(p3, b3, ao); ao = fmaf(n3, a3, ao);
  }
  for (; k < k1; ++k) {
    float p = pos[k], n = neg[k];
    float a = Uq[0], b = Oq[0];
    Uq += st; Oq += st;
    au = fmaf(p, a, au); au = fmaf(n, b, au);
    ao = fmaf(p, b, ao); ao = fmaf(n, a, ao);
  }
  pu[(size_t)chunk * ps + j] = au;
  po[(size_t)chunk * ps + j] = ao;
}

// ---------------------------------------------------------------------------
// Dispatch B (pow2 path): fill both IBF tensors AND finish row 0 inline.
// One float4 = rows r0, r0+1 (cols 0..1 each) of one block. Threads whose
// float4 starts a block (within==0 -> row 0) reduce the GEMV partials for
// their block's coefficient (visible: dispatch A completed in stream order),
// add bias, scale .x/.y. Also writes the ones degree vectors.
// ---------------------------------------------------------------------------
__global__ __launch_bounds__(TPB) void fill_finish(
    const float* __restrict__ intervals,
    const float* __restrict__ pu, const float* __restrict__ po,
    const float* __restrict__ bias_p,
    float* __restrict__ outU, float* __restrict__ outO,
    float* __restrict__ degs,
    int n_vars, int shift, int mask, int n4total, int nchunks, int ps) {
  int i4 = blockIdx.x * TPB + threadIdx.x;
  if (i4 < 2 * n_vars) degs[i4] = 1.0f;
  if (i4 >= n4total) return;

  int i = i4 << 2;
  int blk = i >> shift;          // block index in [0, n_vars]
  int within = i & mask;         // multiple of 4
  int r0 = within >> 1;          // even row; float4 = rows r0, r0+1

  float4 v = make_float4(1.f, 1.f, 1.f, 1.f);
  if (r0 == blk) {               // diag at even row (never hits blk==n_vars)
    v.x = intervals[2 * blk];
    v.y = intervals[2 * blk + 1];
  } else if (r0 + 1 == blk) {    // diag at odd row
    v.z = intervals[2 * blk];
    v.w = intervals[2 * blk + 1];
  }

  float4 vu = v, vo = v;
  if (within == 0) {             // this float4 holds rows 0 and 1
    float bb = bias_p[0];
    float su = bb, so = bb;
#pragma unroll 8
    for (int c = 0; c < nchunks; ++c) {
      su += pu[(size_t)c * ps + blk];
      so += po[(size_t)c * ps + blk];
    }
    vu.x = v.x * su; vu.y = v.y * su;
    vo.x = v.x * so; vo.y = v.y * so;
  }

  reinterpret_cast<float4*>(outU)[i4] = vu;
  reinterpret_cast<float4*>(outO)[i4] = vo;
}

// ---------------------------------------------------------------------------
// Generic fallbacks (non-pow2 n_vars): base fill + separate finisher.
// ---------------------------------------------------------------------------
__global__ __launch_bounds__(TPB) void fill_scalar(
    const float* __restrict__ intervals,
    float* __restrict__ outU, float* __restrict__ outO,
    int n_vars, long long S) {
  long long tid = (long long)blockIdx.x * blockDim.x + threadIdx.x;
  long long nthreads = (long long)gridDim.x * blockDim.x;
  int two_n = 2 * n_vars;
  for (long long i = tid; i < S; i += nthreads) {
    int blk = (int)(i / two_n);
    int within = (int)(i - (long long)blk * two_n);
    int r = within >> 1;
    int c = within & 1;
    float v = 1.f;
    if (r == blk) v = intervals[2 * r + c];
    outU[i] = v;
    outO[i] = v;
  }
}

__global__ __launch_bounds__(TPB) void finish(
    const float* __restrict__ pu, const float* __restrict__ po,
    const float* __restrict__ intervals, const float* __restrict__ bias_p,
    float* __restrict__ outU, float* __restrict__ outO,
    float* __restrict__ degs,
    int ncols, int n_vars, int nchunks, int ps) {
  int t = blockIdx.x * TPB + threadIdx.x;
  int two_n = 2 * n_vars;
  if (t < two_n) degs[t] = 1.0f;
  if (t < ncols) {
    float s = bias_p[0];
    for (int c = 0; c < nchunks; ++c) s += pu[(size_t)c * ps + t];
    float vx = s, vy = s;
    if (t == 0) { vx = intervals[0] * s; vy = intervals[1] * s; }
    size_t off = (size_t)t * two_n;
    outU[off] = vx; outU[off + 1] = vy;
  } else if (t < 2 * ncols) {
    int j = t - ncols;
    float s = bias_p[0];
    for (int c = 0; c < nchunks; ++c) s += po[(size_t)c * ps + j];
    float vx = s, vy = s;
    if (j == 0) { vx = intervals[0] * s; vy = intervals[1] * s; }
    size_t off = (size_t)j * two_n;
    outO[off] = vx; outO[off + 1] = vy;
  }
}

extern "C" void kernel_launch(void* const* d_in, const int* in_sizes, int n_in,
                              void* d_out, int out_size, void* d_ws, size_t ws_size,
                              hipStream_t stream) {
  const float* U         = (const float*)d_in[0];  // (K, n_vars+1)
  const float* O         = (const float*)d_in[1];  // (K, n_vars+1)
  const float* intervals = (const float*)d_in[4];  // (n_vars, 2)
  const float* pos       = (const float*)d_in[5];  // (K,)
  const float* neg       = (const float*)d_in[6];  // (K,)
  const float* bias      = (const float*)d_in[7];  // (1,)

  const int n_vars = in_sizes[4] / 2;
  const int K      = in_sizes[5];
  const int ncols  = n_vars + 1;
  const int ps     = (ncols + 7) & ~7;   // padded partial stride

  // 64 K-chunks x 17 col tiles = 1088 blocks (4+ blocks/CU wave of work).
  int nchunks = 64;
  while (nchunks > 1 && (size_t)2 * nchunks * ps * sizeof(float) > ws_size)
    nchunks >>= 1;
  const int rpc = (K + nchunks - 1) / nchunks;
  float* pu = (float*)d_ws;
  float* po = pu + (size_t)nchunks * ps;

  const int col_tiles = (ncols + TPB - 1) / TPB;

  // Dispatch A: GEMV partials (read-bound, ~134 MB fetch).
  gemv4<<<nchunks * col_tiles, TPB, 0, stream>>>(
      U, O, pos, neg, pu, po, K, ncols, ps, col_tiles, rpc);

  const long long S = (long long)ncols * n_vars * 2;  // elements per tensor
  float* outU = (float*)d_out;
  float* outO = outU + S;
  float* degs = outU + 2 * S;

  const int two_n = 2 * n_vars;
  const bool pow2 = two_n > 0 && (two_n & (two_n - 1)) == 0;

  if (pow2 && S / 4 < (1LL << 31)) {
    // Dispatch B: fill + inline finish (write-bound, ~269 MB write).
    int shift = __builtin_ctz((unsigned)two_n);
    int n4 = (int)(S / 4);
    long long nthreads = n4 > two_n ? n4 : two_n;
    int blocks = (int)((nthreads + TPB - 1) / TPB);
    fill_finish<<<blocks, TPB, 0, stream>>>(
        intervals, pu, po, bias, outU, outO, degs,
        n_vars, shift, two_n - 1, n4, nchunks, ps);
  } else {
    fill_scalar<<<4096, TPB, 0, stream>>>(intervals, outU, outO, n_vars, S);
    int nB = (2 * ncols > two_n ? 2 * ncols : two_n);
    finish<<<(nB + TPB - 1) / TPB, TPB, 0, stream>>>(
        pu, po, intervals, bias, outU, outO, degs, ncols, n_vars, nchunks, ps);
  }
}